// Round 12
// baseline (241.324 us; speedup 1.0000x reference)
//
#include <hip/hip_runtime.h>
#include <stdint.h>

// ROUND-12: dual-matrix per WAVE (instruction-level anti-phase).
// R3/R11 falsified wave-level overlap (phase-locked / barrier-coupled).
// Here each wave braids TWO independent matrices' instruction streams at
// unit granularity: matrix-1 MFMAs fill matrix-0 pk/latency gaps and vice
// versa -- overlap enforced by the scheduler, independent of wave phasing.
// 256 blocks x 256 thr (4 waves), 1 block/CU, 6 planes (48KB), 4 barriers
// per iteration. Per-matrix schedule/numerics IDENTICAL to R9 (verified):
//   STG: gradprox + stage -> T(m)      [bar A]
//   HEAD: afm(identity), m2, m3 + T3   [bar B]
//   TAIL: m6,m9,m12,m15 + T15          [bar D]
//   FRONT: trace [bar E] m30,m45,m60, m63 mirror acc (f32, reg-local)
// Carried: R9 column-strided ownership + register-local gradprox + identity
// one-hot chain head; R8 pi-relabeled fragments (permlane-free repack);
// R7 med3 prox; R6 3-plane chain (B in {T(m), T3, T15}).
// setprio dropped: 1 wave/SIMD -> nothing to arbitrate.
// Plane format: bf16, stride 64, XOR-swizzled:
//   off(X,Y) = X*64 + (((Y>>3) ^ (X&7))<<3) + (Y&7); Y-axis pi-labeled,
//   pi(16b+4g+j) = 32(b>>1)+8g+4(b&1)+j.
#define PL 4096  // shorts per plane

typedef unsigned int u32;
typedef unsigned short u16;
typedef float f32x4 __attribute__((ext_vector_type(4)));
typedef short short8 __attribute__((ext_vector_type(8)));

__device__ __forceinline__ u32 prm(u32 a, u32 b, u32 s) {
  return __builtin_amdgcn_perm(a, b, s);
}
__device__ __forceinline__ u32 pk(float f0, float f1) {  // {bf16 f0, bf16 f1}
  return prm(__float_as_uint(f1), __float_as_uint(f0), 0x07060302u);
}
__device__ __forceinline__ float rlo(u32 w) { return __uint_as_float(w << 16); }
__device__ __forceinline__ float rhi(u32 w) {
  return __uint_as_float(w & 0xffff0000u);
}
__device__ __forceinline__ short8 mk8(u32 w0, u32 w1, u32 w2, u32 w3) {
  union {
    u32 w[4];
    short8 s;
  } u;
  u.w[0] = w0;
  u.w[1] = w1;
  u.w[2] = w2;
  u.w[3] = w3;
  return u.s;
}
__device__ __forceinline__ void dot8(short8 a, short8 b, float& part) {
  union {
    short8 s;
    u32 w[4];
  } ua, ub;
  ua.s = a;
  ub.s = b;
#pragma unroll
  for (int w = 0; w < 4; ++w) {
    part = fmaf(rlo(ua.w[w]), rlo(ub.w[w]), part);
    part = fmaf(rhi(ua.w[w]), rhi(ub.w[w]), part);
  }
}
__device__ __forceinline__ f32x4 MF(short8 a, short8 b, f32x4 c) {
  return __builtin_amdgcn_mfma_f32_16x16x32_bf16(a, b, c, 0, 0, 0);
}

struct AF {
  short8 a0, a1;
};  // A-frags of the wave's row band: pi-positions [0,32) and [32,64)
struct BF8 {
  short8 b[4][2];
};  // B-frags: 4 col tiles x 2 k-halves (pi-positions)

// Mirror acc tiles b -> next A-frags (pi-relabeled: pure register naming).
__device__ __forceinline__ AF macc_to_af(const f32x4 (&m)[4]) {
  u32 P0[4], P1[4];
#pragma unroll
  for (int b = 0; b < 4; ++b) {
    P0[b] = pk(m[b][0], m[b][1]);
    P1[b] = pk(m[b][2], m[b][3]);
  }
  AF r;
  r.a0 = mk8(P0[0], P1[0], P0[1], P1[1]);
  r.a1 = mk8(P0[2], P1[2], P0[3], P1[3]);
  return r;
}

__device__ __forceinline__ BF8 loadBF(const u16* __restrict__ P,
                                      const int (&rb)[4][2]) {
  BF8 f;
#pragma unroll
  for (int b = 0; b < 4; ++b) {
    f.b[b][0] = *(const short8*)(P + rb[b][0]);
    f.b[b][1] = *(const short8*)(P + rb[b][1]);
  }
  return f;
}

__device__ __forceinline__ AF mirrorAF(const AF& a, const BF8& bf) {
  const f32x4 Z = {0.0f, 0.0f, 0.0f, 0.0f};
  f32x4 m[4];
#pragma unroll
  for (int b = 0; b < 4; ++b) {
    m[b] = MF(bf.b[b][0], a.a0, Z);
    m[b] = MF(bf.b[b][1], a.a1, m[b]);
  }
  return macc_to_af(m);
}

__device__ __forceinline__ void primaryT(const AF& a, const BF8& bf,
                                         u16* __restrict__ P,
                                         const int (&sT)[4]) {
  const f32x4 Z = {0.0f, 0.0f, 0.0f, 0.0f};
#pragma unroll
  for (int b = 0; b < 4; ++b) {
    f32x4 p = MF(a.a0, bf.b[b][0], Z);
    p = MF(a.a1, bf.b[b][1], p);
    *(uint2*)(P + sT[b]) = make_uint2(pk(p[0], p[1]), pk(p[2], p[3]));
  }
}

__device__ __forceinline__ float tracePart(const AF& a, const BF8& bf, int w) {
  short8 c0s = bf.b[0][0], c1s = bf.b[0][1];
  if (w == 1) {
    c0s = bf.b[1][0];
    c1s = bf.b[1][1];
  } else if (w == 2) {
    c0s = bf.b[2][0];
    c1s = bf.b[2][1];
  } else if (w == 3) {
    c0s = bf.b[3][0];
    c1s = bf.b[3][1];
  }
  float part = 0.0f;
  dot8(a.a0, c0s, part);
  dot8(a.a1, c1s, part);
#pragma unroll
  for (int off = 1; off < 64; off <<= 1) part += __shfl_xor(part, off);
  return part;
}

__global__ __launch_bounds__(256, 1) void dag_iter_kernel(
    const float* __restrict__ adj, float* __restrict__ out) {
  __shared__ __align__(16) u16 BUF[6 * PL];
  __shared__ float red[8];
  u16* SM0 = BUF;
  u16* P10 = BUF + PL;
  u16* P20 = BUF + 2 * PL;
  u16* SM1 = BUF + 3 * PL;
  u16* P11 = BUF + 4 * PL;
  u16* P21 = BUF + 5 * PL;

  const int tid = (int)threadIdx.x;
  const int lane = tid & 63;
  const int w = tid >> 6;  // row band 0..3
  const int l15 = lane & 15;
  const int grp = lane >> 4;
  const int l7 = l15 & 7;

  const int c = 16 * w + l15;  // owned column (both matrices)
  int rb[4][2];
#pragma unroll
  for (int b = 0; b < 4; ++b)
#pragma unroll
    for (int kh = 0; kh < 2; ++kh)
      rb[b][kh] = (16 * b + l15) * 64 + ((((kh << 2) + grp) ^ l7) << 3);
  int sT[4];
#pragma unroll
  for (int b = 0; b < 4; ++b)
    sT[b] = (16 * b + l15) * 64 +
            ((((grp + ((w >> 1) << 2)) ^ ((16 * b + l15) & 7))) << 3) +
            ((w & 1) << 2);
  int stT[2];
#pragma unroll
  for (int h = 0; h < 2; ++h)
    stT[h] = c * 64 + ((((h << 2) + grp) ^ (c & 7)) << 3);

  // afI: one-hot identity A-fragment, 1.0bf16 at pi-position pi(c).
  AF afI;
  {
    const bool mine = (grp == (l15 >> 2));
    const int s = ((w & 1) << 2) + (l15 & 3);  // slot 0..7
    const u32 onev = (s & 1) ? 0x3F800000u : 0x00003F80u;
    u32 ww[4];
#pragma unroll
    for (int k = 0; k < 4; ++k) ww[k] = (mine && ((s >> 1) == k)) ? onev : 0u;
    short8 hot = mk8(ww[0], ww[1], ww[2], ww[3]);
    short8 zero = mk8(0u, 0u, 0u, 0u);
    afI.a0 = (w < 2) ? hot : zero;
    afI.a1 = (w < 2) ? zero : hot;
  }

  // Per-matrix state. x[b][j] = x[r][c], r = 16b+4g+j.
  const float* src0 = adj + (size_t)(2 * blockIdx.x) * 4096;
  const float* src1 = adj + (size_t)(2 * blockIdx.x + 1) * 4096;
  float x0[4][4], sc0[4][4], x1[4][4], sc1[4][4];
#pragma unroll
  for (int b = 0; b < 4; ++b)
#pragma unroll
    for (int j = 0; j < 4; ++j) {
      const int off = (16 * b + 4 * grp + j) * 64 + c;
      float v0 = src0[off];
      float v1 = src1[off];
      x0[b][j] = v0;
      sc0[b][j] = (v0 > 0.5f) ? v0 : 0.0f;
      x1[b][j] = v1;
      sc1[b][j] = (v1 > 0.5f) ? v1 : 0.0f;
    }
  float alpha0 = 0.0f, alpha1 = 0.0f;
  AF af0, af1;               // af(m15): TAIL -> FRONT
  BF8 bf3_0, bf3_1;          // B-frags of m3 (T3): TAIL -> FRONT (m63)
  f32x4 a63_0[4], a63_1[4];  // m63 mirror accs (f32), FRONT -> STG

  auto proxOne = [&](const float (&til)[4][4], float (&xx)[4][4]) {
#pragma unroll
    for (int b = 0; b < 4; ++b)
#pragma unroll
      for (int j = 0; j < 4; ++j) {
        float ax = fabsf(til[b][j]) - 2e-5f;
        xx[b][j] = fminf(fmaxf(ax, 0.0f), 1.0f);  // -> v_med3_f32
      }
  };
  auto gradproxOne = [&](float (&xx)[4][4], const float (&scc)[4][4],
                         float& al, const f32x4 (&a63)[4], int rbase) {
    float tr = red[rbase] + red[rbase + 1] + red[rbase + 2] + red[rbase + 3];
    al = fmaf(0.01f, tr * 0.015625f - 1.0f, al);
    const float a2 = al * 0.03125f;  // 2*alpha/64
    float til[4][4];
#pragma unroll
    for (int b = 0; b < 4; ++b)
#pragma unroll
      for (int j = 0; j < 4; ++j) {
        float g = fmaf(a2 * xx[b][j], a63[b][j], -scc[b][j]);
        til[b][j] = fmaf(-0.01f, g, xx[b][j]);
      }
    proxOne(til, xx);
  };
  auto stageOne = [&](const float (&xx)[4][4], u16* SMp) {
    float m[4][4];
#pragma unroll
    for (int b = 0; b < 4; ++b)
#pragma unroll
      for (int j = 0; j < 4; ++j)
        m[b][j] = fmaf(xx[b][j] * xx[b][j], 0.015625f,
                       (b == w && 4 * grp + j == l15) ? 1.0f : 0.0f);
#pragma unroll
    for (int h = 0; h < 2; ++h)
      *(short8*)(SMp + stT[h]) =
          mk8(pk(m[2 * h][0], m[2 * h][1]), pk(m[2 * h][2], m[2 * h][3]),
              pk(m[2 * h + 1][0], m[2 * h + 1][1]),
              pk(m[2 * h + 1][2], m[2 * h + 1][3]));
  };

  auto segHEADTAIL = [&]() {
    // HEAD: afm, m2, m3 (interleaved dual streams); T3 primaries.
    BF8 bm0 = loadBF(SM0, rb);
    BF8 bm1 = loadBF(SM1, rb);
    AF afm0 = mirrorAF(afI, bm0);
    AF afm1 = mirrorAF(afI, bm1);
    AF af2_0 = mirrorAF(afm0, bm0);
    AF af2_1 = mirrorAF(afm1, bm1);
    AF af3a = mirrorAF(af2_0, bm0);
    AF af3b = mirrorAF(af2_1, bm1);
    primaryT(af2_0, bm0, P10, sT);
    primaryT(af2_1, bm1, P11, sT);
    __syncthreads();  // B
    // TAIL: m6,m9,m12,m15 (interleaved); T15 primaries.
    bf3_0 = loadBF(P10, rb);
    bf3_1 = loadBF(P11, rb);
    AF af6_0 = mirrorAF(af3a, bf3_0);
    AF af6_1 = mirrorAF(af3b, bf3_1);
    AF af9_0 = mirrorAF(af6_0, bf3_0);
    AF af9_1 = mirrorAF(af6_1, bf3_1);
    AF af12_0 = mirrorAF(af9_0, bf3_0);
    AF af12_1 = mirrorAF(af9_1, bf3_1);
    af0 = mirrorAF(af12_0, bf3_0);
    af1 = mirrorAF(af12_1, bf3_1);
    primaryT(af12_0, bf3_0, P20, sT);
    primaryT(af12_1, bf3_1, P21, sT);
    __syncthreads();  // D
  };
  auto segFRONT = [&]() {
    BF8 b15_0 = loadBF(P20, rb);
    BF8 b15_1 = loadBF(P21, rb);
    float p0 = tracePart(af0, b15_0, w);
    float p1 = tracePart(af1, b15_1, w);
    if (lane == 0) {
      red[w] = p0;
      red[4 + w] = p1;
    }
    __syncthreads();  // E (red sync; padded by the mirrors below)
    AF af30_0 = mirrorAF(af0, b15_0);
    AF af30_1 = mirrorAF(af1, b15_1);
    AF af45_0 = mirrorAF(af30_0, b15_0);
    AF af45_1 = mirrorAF(af30_1, b15_1);
    AF af60_0 = mirrorAF(af45_0, b15_0);
    AF af60_1 = mirrorAF(af45_1, b15_1);
    const f32x4 Z = {0.0f, 0.0f, 0.0f, 0.0f};
#pragma unroll
    for (int b = 0; b < 4; ++b) {
      a63_0[b] = MF(bf3_0.b[b][0], af60_0.a0, Z);
      a63_1[b] = MF(bf3_1.b[b][0], af60_1.a0, Z);
      a63_0[b] = MF(bf3_0.b[b][1], af60_0.a1, a63_0[b]);
      a63_1[b] = MF(bf3_1.b[b][1], af60_1.a1, a63_1[b]);
    }
  };

  // ---- iteration 0: alpha == 0 -> grad = -scores ----
  {
    float til0[4][4], til1[4][4];
#pragma unroll
    for (int b = 0; b < 4; ++b)
#pragma unroll
      for (int j = 0; j < 4; ++j) {
        til0[b][j] = fmaf(0.01f, sc0[b][j], x0[b][j]);
        til1[b][j] = fmaf(0.01f, sc1[b][j], x1[b][j]);
      }
    proxOne(til0, x0);
    proxOne(til1, x1);
    stageOne(x0, SM0);
    stageOne(x1, SM1);
    __syncthreads();  // A
    segHEADTAIL();
  }
  // ---- iterations 1..48 ----
  for (int it = 0; it < 48; ++it) {
    segFRONT();
    gradproxOne(x0, sc0, alpha0, a63_0, 0);
    gradproxOne(x1, sc1, alpha1, a63_1, 4);
    stageOne(x0, SM0);
    stageOne(x1, SM1);
    __syncthreads();  // A
    segHEADTAIL();
  }
  // ---- iteration 49: front + gradprox, no trailing stage/chain ----
  segFRONT();
  gradproxOne(x0, sc0, alpha0, a63_0, 0);
  gradproxOne(x1, sc1, alpha1, a63_1, 4);

  float* dst0 = out + (size_t)(2 * blockIdx.x) * 4096;
  float* dst1 = out + (size_t)(2 * blockIdx.x + 1) * 4096;
#pragma unroll
  for (int b = 0; b < 4; ++b)
#pragma unroll
    for (int j = 0; j < 4; ++j) {
      const int off = (16 * b + 4 * grp + j) * 64 + c;
      float v0 = x0[b][j];
      float v1 = x1[b][j];
      dst0[off] = (v0 > 0.5f) ? v0 : 0.0f;
      dst1[off] = (v1 > 0.5f) ? v1 : 0.0f;
    }
}

extern "C" void kernel_launch(void* const* d_in, const int* in_sizes, int n_in,
                              void* d_out, int out_size, void* d_ws,
                              size_t ws_size, hipStream_t stream) {
  const float* adj = (const float*)d_in[0];
  float* out = (float*)d_out;
  const int nbatch = in_sizes[0] / 4096;  // 512
  dag_iter_kernel<<<nbatch / 2, 256, 0, stream>>>(adj, out);
}

// Round 13
// 183.868 us; speedup vs baseline: 1.3125x; 1.3125x over previous
//
#include <hip/hip_runtime.h>
#include <stdint.h>

// ROUND-13: revert to the verified R9 optimum (144 us rocprof / 183 harness).
// R10-R12 falsified the remaining overlap hypotheses (skewed shared-barrier
// TLP: 168 us; dual-matrix-per-wave ILP: 204 us, VGPR 160 -> 1 wave/SIMD).
// R9's loose two-block-per-CU arrangement is the empirical optimum of this
// structure; MFMA-pipe demand ~4035 cyc/SIMD/iter (58% of wall), remaining
// non-overlap is the in-order issue + serial power-chain dependency, which
// five restructurings failed to beat.
//
// Structure (all measured-verified):
//  - column-strided ownership: lane (w,g,l15) owns x[r][c], c=16w+l15,
//    r in {16b+4g+j}; gradprox reads the m63 MIRROR acc f32 registers
//    directly (no T63 plane, no handoff).
//  - chain head af(m) = mirror(afI, bm) with afI = one-hot identity
//    A-fragment (MFMA-pipe transpose of the staged T(m) plane).
//  - R8 pi-relabeled fragments: pi(16b+4g+j)=32(b>>1)+8g+4(b&1)+j makes
//    macc_to_af pure register naming (8 pk, zero permlanes).
//  - R6 3-plane power chain: T(m): m2,m3 ; T3: m6,m9,m12,m15,m63 ;
//    T15: m30,m45,m60.  Barriers/iter: A (stage), B (T3), D (T15), E (red).
//  - R7: med3 prox, setprio around MFMA clusters, de-phased blocks.
// Plane format: bf16, stride 64, XOR-swizzled:
//   off(X,Y) = X*64 + (((Y>>3) ^ (X&7))<<3) + (Y&7); Y-axis pi-labeled.
#define PL 4096  // shorts per plane

typedef unsigned int u32;
typedef unsigned short u16;
typedef float f32x4 __attribute__((ext_vector_type(4)));
typedef short short8 __attribute__((ext_vector_type(8)));

__device__ __forceinline__ u32 prm(u32 a, u32 b, u32 s) {
  return __builtin_amdgcn_perm(a, b, s);
}
__device__ __forceinline__ u32 pk(float f0, float f1) {  // {bf16 f0, bf16 f1}
  return prm(__float_as_uint(f1), __float_as_uint(f0), 0x07060302u);
}
__device__ __forceinline__ float rlo(u32 w) { return __uint_as_float(w << 16); }
__device__ __forceinline__ float rhi(u32 w) {
  return __uint_as_float(w & 0xffff0000u);
}
__device__ __forceinline__ short8 mk8(u32 w0, u32 w1, u32 w2, u32 w3) {
  union {
    u32 w[4];
    short8 s;
  } u;
  u.w[0] = w0;
  u.w[1] = w1;
  u.w[2] = w2;
  u.w[3] = w3;
  return u.s;
}
__device__ __forceinline__ void dot8(short8 a, short8 b, float& part) {
  union {
    short8 s;
    u32 w[4];
  } ua, ub;
  ua.s = a;
  ub.s = b;
#pragma unroll
  for (int w = 0; w < 4; ++w) {
    part = fmaf(rlo(ua.w[w]), rlo(ub.w[w]), part);
    part = fmaf(rhi(ua.w[w]), rhi(ub.w[w]), part);
  }
}
__device__ __forceinline__ f32x4 MF(short8 a, short8 b, f32x4 c) {
  return __builtin_amdgcn_mfma_f32_16x16x32_bf16(a, b, c, 0, 0, 0);
}

struct AF {
  short8 a0, a1;
};  // A-frags of the wave's row band: pi-positions [0,32) and [32,64)
struct BF8 {
  short8 b[4][2];
};  // B-frags: 4 col tiles x 2 k-halves (pi-positions)

// Mirror acc tiles b: lane = row 16w+l15; P0[b]=cols 16b+4g+{0,1},
// P1[b]=cols 16b+4g+{2,3}. pi puts these exactly at a0/a1 word slots.
__device__ __forceinline__ AF macc_to_af(const f32x4 (&m)[4]) {
  u32 P0[4], P1[4];
#pragma unroll
  for (int b = 0; b < 4; ++b) {
    P0[b] = pk(m[b][0], m[b][1]);
    P1[b] = pk(m[b][2], m[b][3]);
  }
  AF r;
  r.a0 = mk8(P0[0], P1[0], P0[1], P1[1]);
  r.a1 = mk8(P0[2], P1[2], P0[3], P1[3]);
  return r;
}

__global__ __launch_bounds__(256, 2) void dag_iter_kernel(
    const float* __restrict__ adj, float* __restrict__ out) {
  __shared__ __align__(16) u16 BUF[3 * PL];
  __shared__ float red[4];
  u16* SM = BUF;           // T(m)
  u16* P1 = BUF + PL;      // T3
  u16* P2 = BUF + 2 * PL;  // T15

  // De-phase the two co-resident blocks on a CU.
  if ((blockIdx.x >> 8) & 1) __builtin_amdgcn_s_sleep(11);

  const int tid = (int)threadIdx.x;
  const int lane = tid & 63;
  const int wv = tid >> 6;  // row band 0..3
  const int l15 = lane & 15;
  const int grp = lane >> 4;
  const int l7 = l15 & 7;

  const int c = 16 * wv + l15;  // owned column
  int rb[4][2];
#pragma unroll
  for (int b = 0; b < 4; ++b)
#pragma unroll
    for (int kh = 0; kh < 2; ++kh)
      rb[b][kh] = (16 * b + l15) * 64 + ((((kh << 2) + grp) ^ l7) << 3);
  int sT[4];
#pragma unroll
  for (int b = 0; b < 4; ++b)
    sT[b] = (16 * b + l15) * 64 +
            ((((grp + ((wv >> 1) << 2)) ^ ((16 * b + l15) & 7))) << 3) +
            ((wv & 1) << 2);
  int stT[2];
#pragma unroll
  for (int h = 0; h < 2; ++h)
    stT[h] = c * 64 + ((((h << 2) + grp) ^ (c & 7)) << 3);

  // afI: one-hot identity A-fragment, 1.0bf16 at pi-position pi(c).
  AF afI;
  {
    const bool mine = (grp == (l15 >> 2));
    const int s = ((wv & 1) << 2) + (l15 & 3);  // slot 0..7
    const u32 onev = (s & 1) ? 0x3F800000u : 0x00003F80u;
    u32 w[4];
#pragma unroll
    for (int k = 0; k < 4; ++k) w[k] = (mine && ((s >> 1) == k)) ? onev : 0u;
    short8 hot = mk8(w[0], w[1], w[2], w[3]);
    short8 zero = mk8(0u, 0u, 0u, 0u);
    afI.a0 = (wv < 2) ? hot : zero;
    afI.a1 = (wv < 2) ? zero : hot;
  }

  // x[b][j] = x[r][c], r = 16b+4g+j.
  const float* src = adj + (size_t)blockIdx.x * 4096;
  float x[4][4], sc[4][4];
#pragma unroll
  for (int b = 0; b < 4; ++b)
#pragma unroll
    for (int j = 0; j < 4; ++j) {
      float v = src[(16 * b + 4 * grp + j) * 64 + c];
      x[b][j] = v;
      sc[b][j] = (v > 0.5f) ? v : 0.0f;
    }
  float alpha = 0.0f;
  AF af;           // af(m15): chain -> front
  BF8 bf3;         // B-frags of m3 (T3): chain -> m63
  f32x4 acc63[4];  // m63 mirror acc (f32), front -> gradprox

  auto loadBF = [&](const u16* P) {
    BF8 f;
#pragma unroll
    for (int b = 0; b < 4; ++b) {
      f.b[b][0] = *(const short8*)(P + rb[b][0]);
      f.b[b][1] = *(const short8*)(P + rb[b][1]);
    }
    return f;
  };
  auto mirrorAF = [&](const AF& a, const BF8& bf) {  // rows of A*M -> regs
    const f32x4 Z = {0.0f, 0.0f, 0.0f, 0.0f};
    f32x4 m[4];
    __builtin_amdgcn_s_setprio(1);
#pragma unroll
    for (int b = 0; b < 4; ++b) {
      m[b] = MF(bf.b[b][0], a.a0, Z);
      m[b] = MF(bf.b[b][1], a.a1, m[b]);
    }
    __builtin_amdgcn_s_setprio(0);
    return macc_to_af(m);
  };
  auto primaryT = [&](const AF& a, const BF8& bf, u16* P) {  // cols -> T-plane
    const f32x4 Z = {0.0f, 0.0f, 0.0f, 0.0f};
    f32x4 p[4];
    __builtin_amdgcn_s_setprio(1);
#pragma unroll
    for (int b = 0; b < 4; ++b) {
      p[b] = MF(a.a0, bf.b[b][0], Z);
      p[b] = MF(a.a1, bf.b[b][1], p[b]);
    }
    __builtin_amdgcn_s_setprio(0);
#pragma unroll
    for (int b = 0; b < 4; ++b)
      *(uint2*)(P + sT[b]) =
          make_uint2(pk(p[b][0], p[b][1]), pk(p[b][2], p[b][3]));
  };
  auto traceP = [&](const AF& a, const BF8& bf) {  // tr(m30) from m15 frags
    short8 c0s = bf.b[0][0], c1s = bf.b[0][1];
    if (wv == 1) {
      c0s = bf.b[1][0];
      c1s = bf.b[1][1];
    } else if (wv == 2) {
      c0s = bf.b[2][0];
      c1s = bf.b[2][1];
    } else if (wv == 3) {
      c0s = bf.b[3][0];
      c1s = bf.b[3][1];
    }
    float part = 0.0f;
    dot8(a.a0, c0s, part);
    dot8(a.a1, c1s, part);
#pragma unroll
    for (int off = 1; off < 64; off <<= 1) part += __shfl_xor(part, off);
    if (lane == 0) red[wv] = part;
  };

  auto prox = [&](float til[4][4]) {
#pragma unroll
    for (int b = 0; b < 4; ++b)
#pragma unroll
      for (int j = 0; j < 4; ++j) {
        float ax = fabsf(til[b][j]) - 2e-5f;
        x[b][j] = fminf(fmaxf(ax, 0.0f), 1.0f);  // -> v_med3_f32
      }
  };
  auto stage = [&]() {  // m = I + x.*x/64 -> T(m)-plane (SM), 2x b128
    float m[4][4];
#pragma unroll
    for (int b = 0; b < 4; ++b)
#pragma unroll
      for (int j = 0; j < 4; ++j)
        m[b][j] = fmaf(x[b][j] * x[b][j], 0.015625f,
                       (b == wv && 4 * grp + j == l15) ? 1.0f : 0.0f);
#pragma unroll
    for (int h = 0; h < 2; ++h)
      *(short8*)(SM + stT[h]) =
          mk8(pk(m[2 * h][0], m[2 * h][1]), pk(m[2 * h][2], m[2 * h][3]),
              pk(m[2 * h + 1][0], m[2 * h + 1][1]),
              pk(m[2 * h + 1][2], m[2 * h + 1][3]));
    __syncthreads();  // A
  };
  auto gradprox = [&]() {  // m63^T patch = acc63 f32 regs; alpha from red
    float tr = red[0] + red[1] + red[2] + red[3];
    alpha = fmaf(0.01f, tr * 0.015625f - 1.0f, alpha);
    const float a2 = alpha * 0.03125f;  // 2*alpha/64
    float til[4][4];
#pragma unroll
    for (int b = 0; b < 4; ++b)
#pragma unroll
      for (int j = 0; j < 4; ++j) {
        float g = fmaf(a2 * x[b][j], acc63[b][j], -sc[b][j]);
        til[b][j] = fmaf(-0.01f, g, x[b][j]);
      }
    prox(til);
  };

  auto chain = [&]() {  // from SM=T(m): build m15 (af), T3, T15
    BF8 bm = loadBF(SM);
    AF afm = mirrorAF(afI, bm);  // rows of m via identity one-hot
    AF af2 = mirrorAF(afm, bm);  // m2
    AF af3 = mirrorAF(af2, bm);  // m3 rows
    primaryT(af2, bm, P1);       // m3 cols -> T3
    __syncthreads();             // B
    bf3 = loadBF(P1);
    AF af6 = mirrorAF(af3, bf3);   // m6
    AF af9 = mirrorAF(af6, bf3);   // m9
    AF af12 = mirrorAF(af9, bf3);  // m12
    af = mirrorAF(af12, bf3);      // m15 rows (kept for front)
    primaryT(af12, bf3, P2);       // m15 cols -> T15
    __syncthreads();               // D
  };
  auto front = [&]() {  // m30,m45,m60 (B=T15); m63 mirror acc (f32, no pack)
    BF8 b15 = loadBF(P2);
    traceP(af, b15);  // red[wv] = band part of tr(m30)
    __syncthreads();  // E (red sync; padded by the mirrors below)
    AF af30 = mirrorAF(af, b15);
    AF af45 = mirrorAF(af30, b15);
    AF af60 = mirrorAF(af45, b15);
    const f32x4 Z = {0.0f, 0.0f, 0.0f, 0.0f};
    __builtin_amdgcn_s_setprio(1);
#pragma unroll
    for (int b = 0; b < 4; ++b) {
      acc63[b] = MF(bf3.b[b][0], af60.a0, Z);
      acc63[b] = MF(bf3.b[b][1], af60.a1, acc63[b]);
    }
    __builtin_amdgcn_s_setprio(0);
  };

  // ---- iteration 0: alpha == 0 -> grad = -scores ----
  {
    float til[4][4];
#pragma unroll
    for (int b = 0; b < 4; ++b)
#pragma unroll
      for (int j = 0; j < 4; ++j) til[b][j] = fmaf(0.01f, sc[b][j], x[b][j]);
    prox(til);
    stage();
    chain();
  }
  // ---- iterations 1..48 ----
  for (int it = 0; it < 48; ++it) {
    front();
    gradprox();
    stage();
    chain();
  }
  // ---- iteration 49: no trailing stage/chain ----
  front();
  gradprox();

  float* dst = out + (size_t)blockIdx.x * 4096;
#pragma unroll
  for (int b = 0; b < 4; ++b)
#pragma unroll
    for (int j = 0; j < 4; ++j) {
      float v = x[b][j];
      dst[(16 * b + 4 * grp + j) * 64 + c] = (v > 0.5f) ? v : 0.0f;
    }
}

extern "C" void kernel_launch(void* const* d_in, const int* in_sizes, int n_in,
                              void* d_out, int out_size, void* d_ws,
                              size_t ws_size, hipStream_t stream) {
  const float* adj = (const float*)d_in[0];
  float* out = (float*)d_out;
  const int nbatch = in_sizes[0] / 4096;  // 512
  dag_iter_kernel<<<nbatch, 256, 0, stream>>>(adj, out);
}